// Round 3
// baseline (2402.738 us; speedup 1.0000x reference)
//
#include <hip/hip_runtime.h>
#include <hip/hip_bf16.h>

typedef unsigned int u32;
typedef unsigned short u16;
typedef _Float16 f16;
typedef float f32x2 __attribute__((ext_vector_type(2)));
typedef _Float16 f16x2 __attribute__((ext_vector_type(2)));
typedef u32 u32x4 __attribute__((ext_vector_type(4)));

#define LN_EPS 1e-5f
#define T_STEPS 30
#define NAG 4096
#define A_BLK 16        // agents per k_gru block

__device__ __forceinline__ float bf2f(u16 v){
    union { u32 u; float f; } c; c.u = ((u32)v) << 16; return c.f;
}
__device__ __forceinline__ u16 f2bf(float f){
    union { float f; u32 u; } c; c.f = f;
    return (u16)((c.u + 0x7FFFu + ((c.u >> 16) & 1u)) >> 16);
}
__device__ __forceinline__ u32 pk_h2(float a, float b){
    f16x2 h; h[0] = (f16)a; h[1] = (f16)b;
    return __builtin_bit_cast(u32, h);
}
__device__ __forceinline__ f32x2 unpk_h2(u32 p){
    f16x2 h = __builtin_bit_cast(f16x2, p);
    f32x2 r; r[0] = (float)h[0]; r[1] = (float)h[1]; return r;
}
// v_dot2_f32_f16: c += a.x*b.x + a.y*b.y
__device__ __forceinline__ float fdot2u(u32 a, u32 b, float c){
    return __builtin_amdgcn_fdot2(__builtin_bit_cast(f16x2, a),
                                  __builtin_bit_cast(f16x2, b), c, false);
}
// dtype probe: fp32 buffers read as u16 have random mantissa halves at even
// positions (~50% decode to |x|>=128); bf16 weight buffers (|w| < 1) never do.
__device__ __forceinline__ int detect_f32(const void* probe){
    const u16* p = (const u16*)probe;
    int bad = 0;
    #pragma unroll
    for (int i = 0; i < 32; i++){
        u32 e = (p[2*i] >> 7) & 0xFF;
        bad += (e >= 0x86) ? 1 : 0;
    }
    return bad > 4;
}
__device__ __forceinline__ float ldin(const void* p, int i, int F){
    float v;
    if (F) v = ((const float*)p)[i];
    else   v = bf2f(((const u16*)p)[i]);
    return v;
}
__device__ __forceinline__ void wred64(float& s, float& q){
    #pragma unroll
    for (int m = 1; m < 64; m <<= 1){ s += __shfl_xor(s, m); q += __shfl_xor(q, m); }
}
__device__ __forceinline__ void wred32(float& s, float& q){
    #pragma unroll
    for (int m = 1; m < 32; m <<= 1){ s += __shfl_xor(s, m); q += __shfl_xor(q, m); }
}
__device__ __forceinline__ float lrelu(float x){ return fmaxf(x, 0.1f * x); }
__device__ __forceinline__ float sigm(float x){ return 1.0f / (1.0f + __expf(-x)); }
__device__ __forceinline__ float ftanh(float x){ return 1.0f - 2.0f / (1.0f + __expf(2.0f * x)); }
__device__ __forceinline__ void ln128(float a0, float a1, float& o0, float& o1){
    float s = a0 + a1, q = a0*a0 + a1*a1;
    wred64(s, q);
    float m = s * (1.f/128.f), v = q * (1.f/128.f) - m*m;
    float rs = rsqrtf(fmaxf(v, 0.f) + LN_EPS);
    o0 = (a0 - m) * rs; o1 = (a1 - m) * rs;
}

// ---------------- K1: cond embeddings (both dirs): [N,2] -> 64 -> 128 ----------------
__global__ __launch_bounds__(64) void k_cond(
    const void* __restrict__ cond,
    const void* __restrict__ w1a, const void* __restrict__ b1a,
    const void* __restrict__ w2a, const void* __restrict__ b2a,
    const void* __restrict__ w1b, const void* __restrict__ b1b,
    const void* __restrict__ w2b, const void* __restrict__ b2b,
    const void* __restrict__ probe,
    f16* __restrict__ disp)
{
    __shared__ float x1s[64];
    int F = detect_f32(probe);
    int n = blockIdx.x, dir = blockIdx.y, lane = threadIdx.x;
    const void* w1 = dir ? w1b : w1a; const void* b1 = dir ? b1b : b1a;
    const void* w2 = dir ? w2b : w2a; const void* b2 = dir ? b2b : b2a;
    float c0 = ldin(cond, n*2, F), c1 = ldin(cond, n*2+1, F);
    float y = ldin(w1, lane*2, F) * c0 + ldin(w1, lane*2+1, F) * c1 + ldin(b1, lane, F);
    float s = y, q = y*y; wred64(s, q);
    float m = s * (1.f/64.f), v = q * (1.f/64.f) - m*m;
    float rs = rsqrtf(fmaxf(v, 0.f) + LN_EPS);
    x1s[lane] = lrelu((y - m) * rs);
    __syncthreads();
    float y0 = ldin(b2, lane, F), y1 = ldin(b2, lane+64, F);
    for (int k = 0; k < 64; k++){
        float xv = x1s[k];
        y0 += ldin(w2, lane*64+k, F) * xv;
        y1 += ldin(w2, (lane+64)*64+k, F) * xv;
    }
    float o0, o1; ln128(y0, y1, o0, o1);
    f16* dp = disp + ((size_t)dir * NAG + n) * 128;
    dp[lane] = (f16)lrelu(o0);
    dp[lane+64] = (f16)lrelu(o1);
}

// ---------------- K2: scene embedding: z[T,N,128] -> 32 -> 64, store f16 ----------------
__global__ __launch_bounds__(256) void k_emb(
    const void* __restrict__ z,
    const void* __restrict__ iw1, const void* __restrict__ ib1,
    const void* __restrict__ iw2, const void* __restrict__ ib2,
    const void* __restrict__ probe,
    f16* __restrict__ semb)
{
    __shared__ float w1T[128*32];   // [k][e]
    __shared__ float w2T[32*64];    // [k][e]
    __shared__ float zrow[4][128];
    __shared__ float x1s[4][32];
    int F = detect_f32(probe);
    int tid = threadIdx.x;
    for (int i = tid; i < 4096; i += 256){ int e = i >> 7, k = i & 127; w1T[k*32+e] = ldin(iw1, i, F); }
    for (int i = tid; i < 2048; i += 256){ int e = i >> 5, k = i & 31; w2T[k*64+e] = ldin(iw2, i, F); }
    __syncthreads();
    int w = tid >> 6, lane = tid & 63;
    float b1 = (lane < 32) ? ldin(ib1, lane & 31, F) : 0.f;
    float b2 = ldin(ib2, lane, F);
    #pragma unroll 1
    for (int rr = 0; rr < 8; rr++){
        int row = (blockIdx.x * 4 + w) * 8 + rr;   // < 122880
        zrow[w][lane]    = ldin(z, row*128 + lane, F);
        zrow[w][lane+64] = ldin(z, row*128 + 64 + lane, F);
        __syncthreads();
        float y1 = b1;
        if (lane < 32){
            for (int k = 0; k < 128; k++) y1 += zrow[w][k] * w1T[k*32+lane];
        }
        float s = (lane<32)? y1 : 0.f, q = (lane<32)? y1*y1 : 0.f;
        wred32(s, q);
        float m = s*(1.f/32.f), v = q*(1.f/32.f)-m*m, rs = rsqrtf(fmaxf(v,0.f)+LN_EPS);
        if (lane < 32) x1s[w][lane] = lrelu((y1-m)*rs);
        __syncthreads();
        float y2 = b2;
        for (int k = 0; k < 32; k++) y2 += x1s[w][k] * w2T[k*64+lane];
        s = y2; q = y2*y2; wred64(s, q);
        m = s*(1.f/64.f); v = q*(1.f/64.f)-m*m; rs = rsqrtf(fmaxf(v,0.f)+LN_EPS);
        semb[(size_t)row*64+lane] = (f16)lrelu((y2-m)*rs);
    }
}

// ---------------- K3: bidirectional LN-GRU, register-resident weights ----------------
// grid (256, 2), 384 threads = 6 waves. Wave w owns gate-half chunk (gate=w>>1 in
// {r,z,n}, half=w&1): lane's unit row = gate*128 + half*64 + lane. Each lane keeps
// Whh[row][:] (64 f16-pairs) + Wih[row][:] (32 pairs) in VGPRs for all 30 steps.
// h/x live in LDS as f16 pairs (broadcast b128 reads feed v_dot2_f32_f16).
__global__ __launch_bounds__(384, 3) void k_gru(
    const f16* __restrict__ semb, const f16* __restrict__ disp,
    const void* __restrict__ wihA, const void* __restrict__ whhA,
    const void* __restrict__ bihA, const void* __restrict__ bhhA,
    const void* __restrict__ wihB, const void* __restrict__ whhB,
    const void* __restrict__ bihB, const void* __restrict__ bhhB,
    const void* __restrict__ probe,
    f16* __restrict__ hencF, f16* __restrict__ hencB)
{
    __shared__ u32 hbuf[A_BLK][64];          // f16 pairs of h per agent
    __shared__ u32 xbuf[A_BLK][32];          // f16 pairs of x per agent (this step)
    __shared__ float rzbuf[2][2][A_BLK][64]; // [r/z][half][agent][lane]
    __shared__ float redS[6][A_BLK], redQ[6][A_BLK];
    int F = detect_f32(probe);
    int tid = threadIdx.x, dir = blockIdx.y;
    int w = tid >> 6, lane = tid & 63;
    int gate = w >> 1, half = w & 1;
    int row = gate*128 + half*64 + lane;     // unit row in [0,384)
    const void* wih = dir ? wihB : wihA;  const void* whh = dir ? whhB : whhA;
    const void* bih = dir ? bihB : bihA;  const void* bhh = dir ? bhhB : bhhA;
    f16* henc = dir ? hencB : hencF;

    u32 wh[64], wi[32];
    #pragma unroll
    for (int j = 0; j < 64; j++)
        wh[j] = pk_h2(ldin(whh, row*128 + 2*j, F), ldin(whh, row*128 + 2*j + 1, F));
    #pragma unroll
    for (int j = 0; j < 32; j++)
        wi[j] = pk_h2(ldin(wih, row*64 + 2*j, F), ldin(wih, row*64 + 2*j + 1, F));
    float bh = ldin(bhh, row, F), bi = ldin(bih, row, F);

    int nb = blockIdx.x * A_BLK;
    const u32* dispu = (const u32*)disp;
    for (int i = tid; i < A_BLK*64; i += 384){
        int a = i >> 6, k = i & 63;
        hbuf[a][k] = dispu[((size_t)dir*NAG + nb + a)*64 + k];
    }
    const u32* sembu = (const u32*)semb;
    int tx0 = dir ? (T_STEPS-1) : 0;
    for (int i = tid; i < A_BLK*32; i += 384){
        int a = i >> 5, k = i & 31;
        xbuf[a][k] = sembu[((size_t)tx0*NAG + nb + a)*32 + k];
    }
    __syncthreads();

    #pragma unroll 1
    for (int t = 0; t < T_STEPS; t++){
        int tx = dir ? (T_STEPS-1-t) : t;
        float acc[A_BLK], ai[A_BLK];
        #pragma unroll
        for (int a = 0; a < A_BLK; a++){ acc[a] = bh; ai[a] = bi; }
        // hh dots -> acc
        #pragma unroll
        for (int k4 = 0; k4 < 16; k4++){
            u32 w0 = wh[4*k4], w1 = wh[4*k4+1], w2 = wh[4*k4+2], w3 = wh[4*k4+3];
            #pragma unroll
            for (int a = 0; a < A_BLK; a++){
                u32x4 h4 = *(const u32x4*)&hbuf[a][k4*4];
                float c = acc[a];
                c = fdot2u(h4.x, w0, c);
                c = fdot2u(h4.y, w1, c);
                c = fdot2u(h4.z, w2, c);
                c = fdot2u(h4.w, w3, c);
                acc[a] = c;
            }
        }
        // ih dots -> ai
        #pragma unroll
        for (int k4 = 0; k4 < 8; k4++){
            u32 w0 = wi[4*k4], w1 = wi[4*k4+1], w2 = wi[4*k4+2], w3 = wi[4*k4+3];
            #pragma unroll
            for (int a = 0; a < A_BLK; a++){
                u32x4 x4 = *(const u32x4*)&xbuf[a][k4*4];
                float c = ai[a];
                c = fdot2u(x4.x, w0, c);
                c = fdot2u(x4.y, w1, c);
                c = fdot2u(x4.z, w2, c);
                c = fdot2u(x4.w, w3, c);
                ai[a] = c;
            }
        }
        // r/z: pre-activation = acc + ai; LN partials
        if (gate < 2){
            #pragma unroll
            for (int a = 0; a < A_BLK; a++){
                float p = acc[a] + ai[a];
                acc[a] = p;
                float s = p, q = p*p; wred64(s, q);
                if (lane == a){ redS[w][a] = s; redQ[w][a] = q; }
            }
        }
        __syncthreads();                                 // bar1
        if (gate < 2){
            #pragma unroll
            for (int a = 0; a < A_BLK; a++){
                float s = redS[w][a] + redS[w^1][a];
                float q = redQ[w][a] + redQ[w^1][a];
                float m = s*(1.f/128.f), v = q*(1.f/128.f) - m*m;
                float rs = rsqrtf(fmaxf(v, 0.f) + LN_EPS);
                rzbuf[gate][half][a][lane] = sigm((acc[a] - m)*rs);
            }
        }
        __syncthreads();                                 // bar2: rzbuf ready
        if (gate == 2){
            #pragma unroll
            for (int a = 0; a < A_BLK; a++){
                float r = rzbuf[0][half][a][lane];
                float p = ai[a] + r*acc[a];
                acc[a] = p;
                float s = p, q = p*p; wred64(s, q);
                if (lane == a){ redS[w][a] = s; redQ[w][a] = q; }
            }
        } else if (t + 1 < T_STEPS){
            // r/z waves stage x for the next step (xbuf reads of this step are done)
            int txn = dir ? (T_STEPS-2-t) : (t+1);
            int i = w*64 + lane;            // w<4 -> i in [0,256)
            { int a = i >> 5, k = i & 31;
              xbuf[a][k] = sembu[((size_t)txn*NAG + nb + a)*32 + k]; }
            { int i2 = i + 256; int a = i2 >> 5, k = i2 & 31;
              xbuf[a][k] = sembu[((size_t)txn*NAG + nb + a)*32 + k]; }
        }
        __syncthreads();                                 // bar3
        if (gate == 2){
            int wp = w ^ 1;                              // 4 <-> 5
            #pragma unroll
            for (int a = 0; a < A_BLK; a++){
                float s = redS[w][a] + redS[wp][a];
                float q = redQ[w][a] + redQ[wp][a];
                float m = s*(1.f/128.f), v = q*(1.f/128.f) - m*m;
                float rs = rsqrtf(fmaxf(v, 0.f) + LN_EPS);
                float n = ftanh((acc[a] - m)*rs);
                float z = rzbuf[1][half][a][lane];
                u32 hp2 = hbuf[a][half*32 + (lane >> 1)];
                f16x2 hph = __builtin_bit_cast(f16x2, hp2);
                float hp = (float)((lane & 1) ? hph[1] : hph[0]);
                float hn = (1.f - z)*n + z*hp;
                henc[((size_t)tx*NAG + nb + a)*128 + half*64 + lane] = (f16)hn;
                float e0 = __shfl(hn, 2*(lane & 31));
                float e1 = __shfl(hn, 2*(lane & 31) + 1);
                if (lane < 32) hbuf[a][half*32 + lane] = pk_h2(e0, e1);
            }
        }
        __syncthreads();                                 // bar4: hbuf/xbuf ready
    }
}

// ---------------- K4: fused post-GRU: seq -> pairwise(factored) -> out head ----------------
// wave = one (t,scene). Pairwise Linear factored: W(s_i-s_j)+b = u_i - u_j + b.
__global__ __launch_bounds__(256) void k_post(
    const f16* __restrict__ hf, const f16* __restrict__ hb,
    const void* __restrict__ sw, const void* __restrict__ sb,
    const void* __restrict__ mw, const void* __restrict__ mb,
    const void* __restrict__ ow1, const void* __restrict__ ob1,
    const void* __restrict__ ow2, const void* __restrict__ ob2,
    const void* __restrict__ probe,
    void* __restrict__ outp)
{
    __shared__ u32 swp[64*64];     // [kp][unit]: (sw[u][2kp], sw[u][2kp+1])
    __shared__ u32 mwp[32*64];     // [kp][unit]
    __shared__ u32 w1p[64*32];     // [kp][e<32]
    __shared__ u32 xr[4][8][64];   // x=(hf+hb)/2 as f16 pairs, per wave/row
    __shared__ u32 fr[4][8][64];   // full=[seq|ave] pairs: [0,32)=seq, [32,64)=ave
    int F = detect_f32(probe);
    int tid = threadIdx.x;
    for (int i = tid; i < 4096; i += 256){
        int u = i & 63, kp = i >> 6;
        swp[kp*64+u] = pk_h2(ldin(sw, u*128 + 2*kp, F), ldin(sw, u*128 + 2*kp + 1, F));
    }
    for (int i = tid; i < 2048; i += 256){
        int u = i & 63, kp = i >> 6;   // kp < 32
        mwp[kp*64+u] = pk_h2(ldin(mw, u*64 + 2*kp, F), ldin(mw, u*64 + 2*kp + 1, F));
    }
    for (int i = tid; i < 2048; i += 256){
        int e = i & 31, kp = i >> 5;   // kp < 64
        w1p[kp*32+e] = pk_h2(ldin(ow1, e*128 + 2*kp, F), ldin(ow1, e*128 + 2*kp + 1, F));
    }
    int w = tid >> 6, lane = tid & 63;
    int unit = blockIdx.x*4 + w;        // t*512 + scene, < 15360
    int t = unit >> 9, sc = unit & 511;
    int base = sc * 8;
    size_t rowbase = (size_t)t*NAG + base;
    const u32* hfu = (const u32*)hf;
    const u32* hbu = (const u32*)hb;
    #pragma unroll
    for (int r = 0; r < 8; r++){
        f32x2 a = unpk_h2(hfu[(rowbase + r)*64 + lane]);
        f32x2 b = unpk_h2(hbu[(rowbase + r)*64 + lane]);
        xr[w][r][lane] = pk_h2(0.5f*(a[0]+b[0]), 0.5f*(a[1]+b[1]));
    }
    __syncthreads();

    // --- seq = lrelu(LN(sw . x + sb)) ; lane = unit ---
    float bs = ldin(sb, lane, F);
    float y[8];
    #pragma unroll
    for (int r = 0; r < 8; r++) y[r] = bs;
    for (int kp = 0; kp < 64; kp++){
        u32 wv = swp[kp*64 + lane];
        #pragma unroll
        for (int r = 0; r < 8; r++) y[r] = fdot2u(xr[w][r][kp], wv, y[r]);
    }
    #pragma unroll
    for (int r = 0; r < 8; r++){
        float s = y[r], q = y[r]*y[r]; wred64(s, q);
        float m = s*(1.f/64.f), v = q*(1.f/64.f) - m*m;
        float rs = rsqrtf(fmaxf(v, 0.f) + LN_EPS);
        float sv = lrelu((y[r] - m)*rs);
        y[r] = sv;
        float e0 = __shfl(sv, 2*(lane & 31)), e1 = __shfl(sv, 2*(lane & 31) + 1);
        if (lane < 32) fr[w][r][lane] = pk_h2(e0, e1);
    }
    // --- u_i = mw . seq_i (no bias) ---
    float uu[8];
    #pragma unroll
    for (int r = 0; r < 8; r++) uu[r] = 0.f;
    for (int kp = 0; kp < 32; kp++){
        u32 wv = mwp[kp*64 + lane];
        #pragma unroll
        for (int r = 0; r < 8; r++) uu[r] = fdot2u(fr[w][r][kp], wv, uu[r]);
    }
    // --- pairs: y_ij = u_i - u_j + mb ; LN ; lrelu ; mean over j!=i ---
    float bm = ldin(mb, lane, F);
    #pragma unroll
    for (int i = 0; i < 8; i++){
        float acc = 0.f;
        #pragma unroll
        for (int j = 0; j < 8; j++){
            if (j == i) continue;
            float p = uu[i] - uu[j] + bm;
            float s = p, q = p*p; wred64(s, q);
            float m = s*(1.f/64.f), v = q*(1.f/64.f) - m*m;
            float rs = rsqrtf(fmaxf(v, 0.f) + LN_EPS);
            acc += lrelu((p - m)*rs);
        }
        float av = acc * (1.f/7.f);
        float e0 = __shfl(av, 2*(lane & 31)), e1 = __shfl(av, 2*(lane & 31) + 1);
        if (lane < 32) fr[w][i][32 + lane] = pk_h2(e0, e1);
    }
    // --- out head: two rows per pass (lanes 0-31 row rp*2, lanes 32-63 row rp*2+1) ---
    int ll = lane & 31;
    float b1v = ldin(ob1, ll, F);
    float o20 = ldin(ow2, ll, F);
    float o21 = ldin(ow2, 32 + ll, F);
    float bo0 = ldin(ob2, 0, F), bo1 = ldin(ob2, 1, F);
    #pragma unroll
    for (int rp = 0; rp < 4; rp++){
        int r = rp*2 + (lane >> 5);
        float h = b1v;
        for (int kp = 0; kp < 64; kp++)
            h = fdot2u(fr[w][r][kp], w1p[kp*32 + ll], h);
        float s = h, q = h*h; wred32(s, q);
        float m = s*(1.f/32.f), v = q*(1.f/32.f) - m*m;
        float rs = rsqrtf(fmaxf(v, 0.f) + LN_EPS);
        float hv = lrelu((h - m)*rs);
        float p0 = hv*o20, p1 = hv*o21;
        wred32(p0, p1);
        if (ll == 0){
            int n = base + r;
            float v0 = ftanh(p0 + bo0), v1 = ftanh(p1 + bo1);
            size_t i0 = (size_t)(n*2)*T_STEPS + t, i1 = (size_t)(n*2+1)*T_STEPS + t;
            if (F){ ((float*)outp)[i0] = v0; ((float*)outp)[i1] = v1; }
            else  { ((u16*)outp)[i0] = f2bf(v0); ((u16*)outp)[i1] = f2bf(v1); }
        }
    }
}

extern "C" void kernel_launch(void* const* d_in, const int* in_sizes, int n_in,
                              void* d_out, int out_size, void* d_ws, size_t ws_size,
                              hipStream_t stream)
{
    const void* cond = d_in[0];
    const void* z    = d_in[1];
    const void* cw1  = d_in[2];
    const void* cb1  = d_in[3];
    const void* cw2  = d_in[4];
    const void* cb2  = d_in[5];
    const void* cbw1 = d_in[6];
    const void* cbb1 = d_in[7];
    const void* cbw2 = d_in[8];
    const void* cbb2 = d_in[9];
    const void* iw1  = d_in[10];
    const void* ib1  = d_in[11];
    const void* iw2  = d_in[12];
    const void* ib2  = d_in[13];
    const void* wih  = d_in[14];
    const void* whh  = d_in[15];
    const void* bih  = d_in[16];
    const void* bhh  = d_in[17];
    const void* wihb = d_in[18];
    const void* whhb = d_in[19];
    const void* bihb = d_in[20];
    const void* bhhb = d_in[21];
    const void* sw   = d_in[22];
    const void* sb   = d_in[23];
    const void* mw   = d_in[24];
    const void* mb   = d_in[25];
    const void* ow1  = d_in[26];
    const void* ob1  = d_in[27];
    const void* ow2  = d_in[28];
    const void* ob2  = d_in[29];
    const void* probe = whh;   // dtype-detection probe buffer

    char* ws = (char*)d_ws;
    size_t off = 0;
    f16* disp  = (f16*)(ws + off); off += (size_t)2*NAG*128*2;          //  2 MB
    f16* semb  = (f16*)(ws + off); off += (size_t)T_STEPS*NAG*64*2;     // 15.7 MB
    f16* hencF = (f16*)(ws + off); off += (size_t)T_STEPS*NAG*128*2;    // 31.5 MB
    f16* hencB = (f16*)(ws + off); off += (size_t)T_STEPS*NAG*128*2;    // 31.5 MB

    k_cond<<<dim3(NAG,2), 64, 0, stream>>>(cond, cw1,cb1,cw2,cb2, cbw1,cbb1,cbw2,cbb2, probe, disp);
    k_emb<<<3840, 256, 0, stream>>>(z, iw1,ib1,iw2,ib2, probe, semb);
    k_gru<<<dim3(NAG/A_BLK,2), 384, 0, stream>>>(semb, disp, wih,whh,bih,bhh, wihb,whhb,bihb,bhhb, probe, hencF, hencB);
    k_post<<<3840, 256, 0, stream>>>(hencF, hencB, sw,sb, mw,mb, ow1,ob1,ow2,ob2, probe, d_out);
}

// Round 4
// 1350.061 us; speedup vs baseline: 1.7797x; 1.7797x over previous
//
#include <hip/hip_runtime.h>
#include <hip/hip_bf16.h>

typedef unsigned int u32;
typedef unsigned short u16;
typedef _Float16 f16;
typedef float f32x2 __attribute__((ext_vector_type(2)));
typedef _Float16 f16x2 __attribute__((ext_vector_type(2)));
typedef u32 u32x4 __attribute__((ext_vector_type(4)));

#define LN_EPS 1e-5f
#define T_STEPS 30
#define NAG 4096

__device__ __forceinline__ float bf2f(u16 v){
    union { u32 u; float f; } c; c.u = ((u32)v) << 16; return c.f;
}
__device__ __forceinline__ u16 f2bf(float f){
    union { float f; u32 u; } c; c.f = f;
    return (u16)((c.u + 0x7FFFu + ((c.u >> 16) & 1u)) >> 16);
}
__device__ __forceinline__ u32 pk_h2(float a, float b){
    f16x2 h; h[0] = (f16)a; h[1] = (f16)b;
    return __builtin_bit_cast(u32, h);
}
__device__ __forceinline__ f32x2 unpk_h2(u32 p){
    f16x2 h = __builtin_bit_cast(f16x2, p);
    f32x2 r; r[0] = (float)h[0]; r[1] = (float)h[1]; return r;
}
// v_dot2_f32_f16: c += a.x*b.x + a.y*b.y
__device__ __forceinline__ float fdot2u(u32 a, u32 b, float c){
    return __builtin_amdgcn_fdot2(__builtin_bit_cast(f16x2, a),
                                  __builtin_bit_cast(f16x2, b), c, false);
}
// dtype probe: fp32 buffers read as u16 have random mantissa halves at even
// positions (~50% decode to |x|>=128); bf16 weight buffers (|w| < 1) never do.
__device__ __forceinline__ int detect_f32(const void* probe){
    const u16* p = (const u16*)probe;
    int bad = 0;
    #pragma unroll
    for (int i = 0; i < 32; i++){
        u32 e = (p[2*i] >> 7) & 0xFF;
        bad += (e >= 0x86) ? 1 : 0;
    }
    return bad > 4;
}
__device__ __forceinline__ float ldin(const void* p, int i, int F){
    float v;
    if (F) v = ((const float*)p)[i];
    else   v = bf2f(((const u16*)p)[i]);
    return v;
}
__device__ __forceinline__ void wred64(float& s, float& q){
    #pragma unroll
    for (int m = 1; m < 64; m <<= 1){ s += __shfl_xor(s, m); q += __shfl_xor(q, m); }
}
__device__ __forceinline__ void wred32(float& s, float& q){
    #pragma unroll
    for (int m = 1; m < 32; m <<= 1){ s += __shfl_xor(s, m); q += __shfl_xor(q, m); }
}
__device__ __forceinline__ float lrelu(float x){ return fmaxf(x, 0.1f * x); }
__device__ __forceinline__ float sigm(float x){ return 1.0f / (1.0f + __expf(-x)); }
__device__ __forceinline__ float ftanh(float x){ return 1.0f - 2.0f / (1.0f + __expf(2.0f * x)); }
__device__ __forceinline__ void ln128(float a0, float a1, float& o0, float& o1){
    float s = a0 + a1, q = a0*a0 + a1*a1;
    wred64(s, q);
    float m = s * (1.f/128.f), v = q * (1.f/128.f) - m*m;
    float rs = rsqrtf(fmaxf(v, 0.f) + LN_EPS);
    o0 = (a0 - m) * rs; o1 = (a1 - m) * rs;
}

// ---------------- K1: cond embeddings (both dirs): [N,2] -> 64 -> 128 ----------------
__global__ __launch_bounds__(64) void k_cond(
    const void* __restrict__ cond,
    const void* __restrict__ w1a, const void* __restrict__ b1a,
    const void* __restrict__ w2a, const void* __restrict__ b2a,
    const void* __restrict__ w1b, const void* __restrict__ b1b,
    const void* __restrict__ w2b, const void* __restrict__ b2b,
    const void* __restrict__ probe,
    f16* __restrict__ disp)
{
    __shared__ float x1s[64];
    int F = detect_f32(probe);
    int n = blockIdx.x, dir = blockIdx.y, lane = threadIdx.x;
    const void* w1 = dir ? w1b : w1a; const void* b1 = dir ? b1b : b1a;
    const void* w2 = dir ? w2b : w2a; const void* b2 = dir ? b2b : b2a;
    float c0 = ldin(cond, n*2, F), c1 = ldin(cond, n*2+1, F);
    float y = ldin(w1, lane*2, F) * c0 + ldin(w1, lane*2+1, F) * c1 + ldin(b1, lane, F);
    float s = y, q = y*y; wred64(s, q);
    float m = s * (1.f/64.f), v = q * (1.f/64.f) - m*m;
    float rs = rsqrtf(fmaxf(v, 0.f) + LN_EPS);
    x1s[lane] = lrelu((y - m) * rs);
    __syncthreads();
    float y0 = ldin(b2, lane, F), y1 = ldin(b2, lane+64, F);
    for (int k = 0; k < 64; k++){
        float xv = x1s[k];
        y0 += ldin(w2, lane*64+k, F) * xv;
        y1 += ldin(w2, (lane+64)*64+k, F) * xv;
    }
    float o0, o1; ln128(y0, y1, o0, o1);
    f16* dp = disp + ((size_t)dir * NAG + n) * 128;
    dp[lane] = (f16)lrelu(o0);
    dp[lane+64] = (f16)lrelu(o1);
}

// ---------------- K2: scene embedding: z[T,N,128] -> 32 -> 64, store f16 ----------------
__global__ __launch_bounds__(256) void k_emb(
    const void* __restrict__ z,
    const void* __restrict__ iw1, const void* __restrict__ ib1,
    const void* __restrict__ iw2, const void* __restrict__ ib2,
    const void* __restrict__ probe,
    f16* __restrict__ semb)
{
    __shared__ float w1T[128*32];   // [k][e]
    __shared__ float w2T[32*64];    // [k][e]
    __shared__ float zrow[4][128];
    __shared__ float x1s[4][32];
    int F = detect_f32(probe);
    int tid = threadIdx.x;
    for (int i = tid; i < 4096; i += 256){ int e = i >> 7, k = i & 127; w1T[k*32+e] = ldin(iw1, i, F); }
    for (int i = tid; i < 2048; i += 256){ int e = i >> 5, k = i & 31; w2T[k*64+e] = ldin(iw2, i, F); }
    __syncthreads();
    int w = tid >> 6, lane = tid & 63;
    float b1 = (lane < 32) ? ldin(ib1, lane & 31, F) : 0.f;
    float b2 = ldin(ib2, lane, F);
    #pragma unroll 1
    for (int rr = 0; rr < 8; rr++){
        int row = (blockIdx.x * 4 + w) * 8 + rr;   // < 122880
        zrow[w][lane]    = ldin(z, row*128 + lane, F);
        zrow[w][lane+64] = ldin(z, row*128 + 64 + lane, F);
        __syncthreads();
        float y1 = b1;
        if (lane < 32){
            for (int k = 0; k < 128; k++) y1 += zrow[w][k] * w1T[k*32+lane];
        }
        float s = (lane<32)? y1 : 0.f, q = (lane<32)? y1*y1 : 0.f;
        wred32(s, q);
        float m = s*(1.f/32.f), v = q*(1.f/32.f)-m*m, rs = rsqrtf(fmaxf(v,0.f)+LN_EPS);
        if (lane < 32) x1s[w][lane] = lrelu((y1-m)*rs);
        __syncthreads();
        float y2 = b2;
        for (int k = 0; k < 32; k++) y2 += x1s[w][k] * w2T[k*64+lane];
        s = y2; q = y2*y2; wred64(s, q);
        m = s*(1.f/64.f); v = q*(1.f/64.f)-m*m; rs = rsqrtf(fmaxf(v,0.f)+LN_EPS);
        semb[(size_t)row*64+lane] = (f16)lrelu((y2-m)*rs);
    }
}

// ---------------- K3: bidirectional LN-GRU (R2 structure + fdot2 + no per-step barrier) ----
// grid (128, 2): block owns 32 agents (8 waves x 4 agents) for all 30 steps of one
// direction. Weights LDS-resident as f16 pairs [kp][unit] (staged once; VGPR-safe).
// Each wave touches only its own agents' hbuf/xbuf rows -> zero barriers in t-loop.
__global__ __launch_bounds__(512) void k_gru(
    const f16* __restrict__ semb, const f16* __restrict__ disp,
    const void* __restrict__ wihA, const void* __restrict__ whhA,
    const void* __restrict__ bihA, const void* __restrict__ bhhA,
    const void* __restrict__ wihB, const void* __restrict__ whhB,
    const void* __restrict__ bihB, const void* __restrict__ bhhB,
    const void* __restrict__ probe,
    f16* __restrict__ hencF, f16* __restrict__ hencB)
{
    __shared__ u32 WhhT[64*384];   // [kp][u] = (Whh[u][2kp], Whh[u][2kp+1]) f16 pair
    __shared__ u32 WihT[32*384];   // [kp][u]
    __shared__ float brz[256];     // bih[u]+bhh[u] for u<256 (r,z gates)
    __shared__ float bin[128];     // bih[256+u]
    __shared__ float bhn[128];     // bhh[256+u]
    __shared__ u32 hbuf[32][64];   // f16 pairs of h per agent
    __shared__ u32 xbuf[32][32];   // f16 pairs of x per agent (this step)
    int F = detect_f32(probe);
    int tid = threadIdx.x, dir = blockIdx.y;
    const void* wih = dir ? wihB : wihA;  const void* whh = dir ? whhB : whhA;
    const void* bih = dir ? bihB : bihA;  const void* bhh = dir ? bhhB : bhhA;
    f16* henc = dir ? hencB : hencF;
    for (int i = tid; i < 24576; i += 512){
        int u = i >> 6, k = i & 63;
        WhhT[k*384 + u] = pk_h2(ldin(whh, u*128 + 2*k, F), ldin(whh, u*128 + 2*k + 1, F));
    }
    for (int i = tid; i < 12288; i += 512){
        int u = i >> 5, k = i & 31;
        WihT[k*384 + u] = pk_h2(ldin(wih, u*64 + 2*k, F), ldin(wih, u*64 + 2*k + 1, F));
    }
    if (tid < 256) brz[tid] = ldin(bih, tid, F) + ldin(bhh, tid, F);
    else if (tid < 384){ bin[tid-256] = ldin(bih, tid, F); bhn[tid-256] = ldin(bhh, tid, F); }
    __syncthreads();   // the ONLY block-wide barrier

    int w = tid >> 6, lane = tid & 63;
    int nb = blockIdx.x * 32 + w * 4;   // first agent of this wave
    const u32* sembu = (const u32*)semb;
    int tx0 = dir ? (T_STEPS-1) : 0;
    float hreg[4][2];
    #pragma unroll
    for (int a = 0; a < 4; a++){
        const f16* dp = disp + ((size_t)dir*NAG + nb + a)*128;
        hreg[a][0] = (float)dp[lane]; hreg[a][1] = (float)dp[lane+64];
        int s0 = (2*lane) & 63, s1 = (2*lane+1) & 63;
        float e0 = __shfl(hreg[a][0], s0), o0 = __shfl(hreg[a][1], s0);
        float e1 = __shfl(hreg[a][0], s1), o1 = __shfl(hreg[a][1], s1);
        hbuf[w*4+a][lane] = pk_h2((lane<32)?e0:o0, (lane<32)?e1:o1);
        if (lane < 32) xbuf[w*4+a][lane] = sembu[((size_t)tx0*NAG + nb + a)*32 + lane];
    }
    // biases hoisted to registers (step-invariant)
    float B_r0 = brz[lane],     B_r1 = brz[64+lane];
    float B_z0 = brz[128+lane], B_z1 = brz[192+lane];
    float B_i0 = bin[lane],     B_i1 = bin[64+lane];
    float B_h0 = bhn[lane],     B_h1 = bhn[64+lane];

    #pragma unroll 1
    for (int t = 0; t < T_STEPS; t++){
        int tx = dir ? (T_STEPS-1-t) : t;
        float A_r0[4], A_r1[4], A_z0[4], A_z1[4], A_h0[4], A_h1[4], A_i0[4], A_i1[4];
        #pragma unroll
        for (int a = 0; a < 4; a++){
            A_r0[a] = B_r0; A_r1[a] = B_r1;
            A_z0[a] = B_z0; A_z1[a] = B_z1;
            A_h0[a] = B_h0; A_h1[a] = B_h1;
            A_i0[a] = B_i0; A_i1[a] = B_i1;
        }
        // hh dots: lane's units u = lane, lane+64 per gate
        #pragma unroll 2
        for (int k4 = 0; k4 < 16; k4++){
            u32x4 h4[4];
            #pragma unroll
            for (int a = 0; a < 4; a++) h4[a] = *(const u32x4*)&hbuf[w*4+a][k4*4];
            #pragma unroll
            for (int kk = 0; kk < 4; kk++){
                const u32* wrow = &WhhT[(k4*4+kk)*384 + lane];
                u32 wr0 = wrow[0],   wr1 = wrow[64];
                u32 wz0 = wrow[128], wz1 = wrow[192];
                u32 wn0 = wrow[256], wn1 = wrow[320];
                #pragma unroll
                for (int a = 0; a < 4; a++){
                    u32 hh = h4[a][kk];
                    A_r0[a] = fdot2u(hh, wr0, A_r0[a]);
                    A_r1[a] = fdot2u(hh, wr1, A_r1[a]);
                    A_z0[a] = fdot2u(hh, wz0, A_z0[a]);
                    A_z1[a] = fdot2u(hh, wz1, A_z1[a]);
                    A_h0[a] = fdot2u(hh, wn0, A_h0[a]);
                    A_h1[a] = fdot2u(hh, wn1, A_h1[a]);
                }
            }
        }
        // ih dots
        #pragma unroll 2
        for (int k4 = 0; k4 < 8; k4++){
            u32x4 x4[4];
            #pragma unroll
            for (int a = 0; a < 4; a++) x4[a] = *(const u32x4*)&xbuf[w*4+a][k4*4];
            #pragma unroll
            for (int kk = 0; kk < 4; kk++){
                const u32* wrow = &WihT[(k4*4+kk)*384 + lane];
                u32 wr0 = wrow[0],   wr1 = wrow[64];
                u32 wz0 = wrow[128], wz1 = wrow[192];
                u32 wn0 = wrow[256], wn1 = wrow[320];
                #pragma unroll
                for (int a = 0; a < 4; a++){
                    u32 xx = x4[a][kk];
                    A_r0[a] = fdot2u(xx, wr0, A_r0[a]);
                    A_r1[a] = fdot2u(xx, wr1, A_r1[a]);
                    A_z0[a] = fdot2u(xx, wz0, A_z0[a]);
                    A_z1[a] = fdot2u(xx, wz1, A_z1[a]);
                    A_i0[a] = fdot2u(xx, wn0, A_i0[a]);
                    A_i1[a] = fdot2u(xx, wn1, A_i1[a]);
                }
            }
        }
        // stage next step's x (wave-private rows; consumed next iteration)
        if (t + 1 < T_STEPS){
            int txn = dir ? (T_STEPS-2-t) : (t+1);
            #pragma unroll
            for (int a = 0; a < 4; a++){
                if (lane < 32) xbuf[w*4+a][lane] = sembu[((size_t)txn*NAG + nb + a)*32 + lane];
            }
        }
        // epilogue per agent
        #pragma unroll
        for (int a = 0; a < 4; a++){
            float g0, g1;
            ln128(A_r0[a], A_r1[a], g0, g1);
            float r0 = sigm(g0), r1 = sigm(g1);
            ln128(A_z0[a], A_z1[a], g0, g1);
            float z0 = sigm(g0), z1 = sigm(g1);
            float p0 = A_i0[a] + r0*A_h0[a], p1 = A_i1[a] + r1*A_h1[a];
            ln128(p0, p1, g0, g1);
            float n0 = ftanh(g0), n1 = ftanh(g1);
            float hn0 = (1.f - z0)*n0 + z0*hreg[a][0];
            float hn1 = (1.f - z1)*n1 + z1*hreg[a][1];
            hreg[a][0] = hn0; hreg[a][1] = hn1;
            f16* hp = henc + ((size_t)tx*NAG + nb + a)*128;
            hp[lane] = (f16)hn0; hp[lane+64] = (f16)hn1;
            int sl0 = (2*lane) & 63, sl1 = (2*lane+1) & 63;
            float e0 = __shfl(hn0, sl0), o0 = __shfl(hn1, sl0);
            float e1 = __shfl(hn0, sl1), o1 = __shfl(hn1, sl1);
            hbuf[w*4+a][lane] = pk_h2((lane<32)?e0:o0, (lane<32)?e1:o1);
        }
        // no barrier: each wave only touches its own hbuf/xbuf rows
    }
}

// ---------------- K4: fused post-GRU: seq -> pairwise(factored) -> out head ----------------
// wave = one (t,scene). Pairwise Linear factored: W(s_i-s_j)+b = u_i - u_j + b.
__global__ __launch_bounds__(256) void k_post(
    const f16* __restrict__ hf, const f16* __restrict__ hb,
    const void* __restrict__ sw, const void* __restrict__ sb,
    const void* __restrict__ mw, const void* __restrict__ mb,
    const void* __restrict__ ow1, const void* __restrict__ ob1,
    const void* __restrict__ ow2, const void* __restrict__ ob2,
    const void* __restrict__ probe,
    void* __restrict__ outp)
{
    __shared__ u32 swp[64*64];     // [kp][unit]: (sw[u][2kp], sw[u][2kp+1])
    __shared__ u32 mwp[32*64];     // [kp][unit]
    __shared__ u32 w1p[64*32];     // [kp][e<32]
    __shared__ u32 xr[4][8][64];   // x=(hf+hb)/2 as f16 pairs, per wave/row
    __shared__ u32 fr[4][8][64];   // full=[seq|ave] pairs: [0,32)=seq, [32,64)=ave
    int F = detect_f32(probe);
    int tid = threadIdx.x;
    for (int i = tid; i < 4096; i += 256){
        int u = i & 63, kp = i >> 6;
        swp[kp*64+u] = pk_h2(ldin(sw, u*128 + 2*kp, F), ldin(sw, u*128 + 2*kp + 1, F));
    }
    for (int i = tid; i < 2048; i += 256){
        int u = i & 63, kp = i >> 6;   // kp < 32
        mwp[kp*64+u] = pk_h2(ldin(mw, u*64 + 2*kp, F), ldin(mw, u*64 + 2*kp + 1, F));
    }
    for (int i = tid; i < 2048; i += 256){
        int e = i & 31, kp = i >> 5;   // kp < 64
        w1p[kp*32+e] = pk_h2(ldin(ow1, e*128 + 2*kp, F), ldin(ow1, e*128 + 2*kp + 1, F));
    }
    int w = tid >> 6, lane = tid & 63;
    int unit = blockIdx.x*4 + w;        // t*512 + scene, < 15360
    int t = unit >> 9, sc = unit & 511;
    int base = sc * 8;
    size_t rowbase = (size_t)t*NAG + base;
    const u32* hfu = (const u32*)hf;
    const u32* hbu = (const u32*)hb;
    #pragma unroll
    for (int r = 0; r < 8; r++){
        f32x2 a = unpk_h2(hfu[(rowbase + r)*64 + lane]);
        f32x2 b = unpk_h2(hbu[(rowbase + r)*64 + lane]);
        xr[w][r][lane] = pk_h2(0.5f*(a[0]+b[0]), 0.5f*(a[1]+b[1]));
    }
    __syncthreads();

    // --- seq = lrelu(LN(sw . x + sb)) ; lane = unit ---
    float bs = ldin(sb, lane, F);
    float y[8];
    #pragma unroll
    for (int r = 0; r < 8; r++) y[r] = bs;
    for (int kp = 0; kp < 64; kp++){
        u32 wv = swp[kp*64 + lane];
        #pragma unroll
        for (int r = 0; r < 8; r++) y[r] = fdot2u(xr[w][r][kp], wv, y[r]);
    }
    #pragma unroll
    for (int r = 0; r < 8; r++){
        float s = y[r], q = y[r]*y[r]; wred64(s, q);
        float m = s*(1.f/64.f), v = q*(1.f/64.f) - m*m;
        float rs = rsqrtf(fmaxf(v, 0.f) + LN_EPS);
        float sv = lrelu((y[r] - m)*rs);
        y[r] = sv;
        float e0 = __shfl(sv, 2*(lane & 31)), e1 = __shfl(sv, 2*(lane & 31) + 1);
        if (lane < 32) fr[w][r][lane] = pk_h2(e0, e1);
    }
    // --- u_i = mw . seq_i (no bias) ---
    float uu[8];
    #pragma unroll
    for (int r = 0; r < 8; r++) uu[r] = 0.f;
    for (int kp = 0; kp < 32; kp++){
        u32 wv = mwp[kp*64 + lane];
        #pragma unroll
        for (int r = 0; r < 8; r++) uu[r] = fdot2u(fr[w][r][kp], wv, uu[r]);
    }
    // --- pairs: y_ij = u_i - u_j + mb ; LN ; lrelu ; mean over j!=i ---
    float bm = ldin(mb, lane, F);
    #pragma unroll
    for (int i = 0; i < 8; i++){
        float acc = 0.f;
        #pragma unroll
        for (int j = 0; j < 8; j++){
            if (j == i) continue;
            float p = uu[i] - uu[j] + bm;
            float s = p, q = p*p; wred64(s, q);
            float m = s*(1.f/64.f), v = q*(1.f/64.f) - m*m;
            float rs = rsqrtf(fmaxf(v, 0.f) + LN_EPS);
            acc += lrelu((p - m)*rs);
        }
        float av = acc * (1.f/7.f);
        float e0 = __shfl(av, 2*(lane & 31)), e1 = __shfl(av, 2*(lane & 31) + 1);
        if (lane < 32) fr[w][i][32 + lane] = pk_h2(e0, e1);
    }
    // --- out head: two rows per pass (lanes 0-31 row rp*2, lanes 32-63 row rp*2+1) ---
    int ll = lane & 31;
    float b1v = ldin(ob1, ll, F);
    float o20 = ldin(ow2, ll, F);
    float o21 = ldin(ow2, 32 + ll, F);
    float bo0 = ldin(ob2, 0, F), bo1 = ldin(ob2, 1, F);
    #pragma unroll
    for (int rp = 0; rp < 4; rp++){
        int r = rp*2 + (lane >> 5);
        float h = b1v;
        for (int kp = 0; kp < 64; kp++)
            h = fdot2u(fr[w][r][kp], w1p[kp*32 + ll], h);
        float s = h, q = h*h; wred32(s, q);
        float m = s*(1.f/32.f), v = q*(1.f/32.f) - m*m;
        float rs = rsqrtf(fmaxf(v, 0.f) + LN_EPS);
        float hv = lrelu((h - m)*rs);
        float p0 = hv*o20, p1 = hv*o21;
        wred32(p0, p1);
        if (ll == 0){
            int n = base + r;
            float v0 = ftanh(p0 + bo0), v1 = ftanh(p1 + bo1);
            size_t i0 = (size_t)(n*2)*T_STEPS + t, i1 = (size_t)(n*2+1)*T_STEPS + t;
            if (F){ ((float*)outp)[i0] = v0; ((float*)outp)[i1] = v1; }
            else  { ((u16*)outp)[i0] = f2bf(v0); ((u16*)outp)[i1] = f2bf(v1); }
        }
    }
}

extern "C" void kernel_launch(void* const* d_in, const int* in_sizes, int n_in,
                              void* d_out, int out_size, void* d_ws, size_t ws_size,
                              hipStream_t stream)
{
    const void* cond = d_in[0];
    const void* z    = d_in[1];
    const void* cw1  = d_in[2];
    const void* cb1  = d_in[3];
    const void* cw2  = d_in[4];
    const void* cb2  = d_in[5];
    const void* cbw1 = d_in[6];
    const void* cbb1 = d_in[7];
    const void* cbw2 = d_in[8];
    const void* cbb2 = d_in[9];
    const void* iw1  = d_in[10];
    const void* ib1  = d_in[11];
    const void* iw2  = d_in[12];
    const void* ib2  = d_in[13];
    const void* wih  = d_in[14];
    const void* whh  = d_in[15];
    const void* bih  = d_in[16];
    const void* bhh  = d_in[17];
    const void* wihb = d_in[18];
    const void* whhb = d_in[19];
    const void* bihb = d_in[20];
    const void* bhhb = d_in[21];
    const void* sw   = d_in[22];
    const void* sb   = d_in[23];
    const void* mw   = d_in[24];
    const void* mb   = d_in[25];
    const void* ow1  = d_in[26];
    const void* ob1  = d_in[27];
    const void* ow2  = d_in[28];
    const void* ob2  = d_in[29];
    const void* probe = whh;   // dtype-detection probe buffer

    char* ws = (char*)d_ws;
    size_t off = 0;
    f16* disp  = (f16*)(ws + off); off += (size_t)2*NAG*128*2;          //  2 MB
    f16* semb  = (f16*)(ws + off); off += (size_t)T_STEPS*NAG*64*2;     // 15.7 MB
    f16* hencF = (f16*)(ws + off); off += (size_t)T_STEPS*NAG*128*2;    // 31.5 MB
    f16* hencB = (f16*)(ws + off); off += (size_t)T_STEPS*NAG*128*2;    // 31.5 MB

    k_cond<<<dim3(NAG,2), 64, 0, stream>>>(cond, cw1,cb1,cw2,cb2, cbw1,cbb1,cbw2,cbb2, probe, disp);
    k_emb<<<3840, 256, 0, stream>>>(z, iw1,ib1,iw2,ib2, probe, semb);
    k_gru<<<dim3(128,2), 512, 0, stream>>>(semb, disp, wih,whh,bih,bhh, wihb,whhb,bihb,bhhb, probe, hencF, hencB);
    k_post<<<3840, 256, 0, stream>>>(hencF, hencB, sw,sb, mw,mb, ow1,ob1,ow2,ob2, probe, d_out);
}